// Round 1
// baseline (311.633 us; speedup 1.0000x reference)
//
#include <hip/hip_runtime.h>
#include <stdint.h>

typedef short s16x8 __attribute__((ext_vector_type(8)));
typedef __bf16 bf16x8 __attribute__((ext_vector_type(8)));
typedef float f32x4 __attribute__((ext_vector_type(4)));

#define NB 8
#define DIM 512
#define DIMO 512
#define DEMB 512
#define NKER 4
#define HH 64
#define WW 64
#define HP 66
#define WP 72
#define KTOT 4608   // 9 * 512

__device__ __forceinline__ unsigned short f2bf(float f) {
  unsigned int u = __builtin_bit_cast(unsigned int, f);
  u += 0x7fffu + ((u >> 16) & 1u);
  return (unsigned short)(u >> 16);
}

// ---------------- kernel 1: sel (softmax over 4) + mod vectors ----------------
__global__ void prep_selmod(const float* __restrict__ embed,
                            const float* __restrict__ adapt_w,
                            const float* __restrict__ adapt_b,
                            const float* __restrict__ mod_w,
                            const float* __restrict__ mod_b,
                            float* __restrict__ sel, float* __restrict__ mod) {
  const int b = blockIdx.x;
  const int t = threadIdx.x;
  const float* e = embed + (size_t)b * DEMB;

  // mod[b][i] = e . mod_w[i] + mod_b[i]
  for (int rep = 0; rep < 2; ++rep) {
    int i = t + rep * 256;
    const float* wrow = mod_w + (size_t)i * DEMB;
    float s = 0.f;
    for (int j = 0; j < DEMB; ++j) s += e[j] * wrow[j];
    mod[b * DIM + i] = s + mod_b[i];
  }

  __shared__ float logits[NKER];
  if (t < NKER) {
    const float* arow = adapt_w + (size_t)t * DEMB;
    float s = 0.f;
    for (int j = 0; j < DEMB; ++j) s += e[j] * arow[j];
    logits[t] = s + adapt_b[t];
  }
  __syncthreads();
  if (t == 0) {
    float m = logits[0];
    for (int n = 1; n < NKER; ++n) m = fmaxf(m, logits[n]);
    float ex[NKER], sum = 0.f;
    for (int n = 0; n < NKER; ++n) { ex[n] = expf(logits[n] - m); sum += ex[n]; }
    for (int n = 0; n < NKER; ++n) sel[b * NKER + n] = ex[n] / sum;
  }
}

// ------- kernel 2: mix + modulate + demodulate weights -> bf16 [b][o][(ky*3+kx)*512+i] -------
__global__ void prep_weights(const float* __restrict__ wbank,
                             const float* __restrict__ sel,
                             const float* __restrict__ mod,
                             unsigned short* __restrict__ wts) {
  const int bo = blockIdx.x;
  const int b = bo >> 9;
  const int o = bo & 511;
  const int t = threadIdx.x;
  const size_t nstride = (size_t)DIMO * DIM * 9;

  __shared__ float v[KTOT];    // permuted (ky,kx,i) order
  __shared__ float red[4];
  __shared__ float invn;

  const float s0 = sel[b * NKER + 0], s1 = sel[b * NKER + 1];
  const float s2 = sel[b * NKER + 2], s3 = sel[b * NKER + 3];
  const float* wb = wbank + (size_t)o * (DIM * 9);
  const float* mo = mod + b * DIM;

  float ss = 0.f;
  for (int r = 0; r < 18; ++r) {
    int ii = t + r * 256;              // input index i*9 + (ky*3+kx), coalesced read
    int i = ii / 9;
    int kykx = ii - i * 9;
    float w = s0 * wb[ii] + s1 * wb[nstride + ii] + s2 * wb[2 * nstride + ii]
            + s3 * wb[3 * nstride + ii];
    w *= (mo[i] + 1.0f);
    v[kykx * 512 + i] = w;
    ss += w * w;
  }
  // block reduction of sum of squares
  const int lane = t & 63, wv = t >> 6;
  for (int off = 32; off > 0; off >>= 1) ss += __shfl_down(ss, off);
  if (lane == 0) red[wv] = ss;
  __syncthreads();
  if (t == 0) {
    float tot = red[0] + red[1] + red[2] + red[3];
    tot = fmaxf(tot, 1e-8f);
    invn = rsqrtf(tot);
  }
  __syncthreads();
  const float inv = invn;
  unsigned short* wo = wts + (size_t)bo * KTOT;
  for (int r = 0; r < 18; ++r) {
    int ok = t + r * 256;              // coalesced write
    wo[ok] = f2bf(v[ok] * inv);
  }
}

// ---------------- kernel 3a: zero padded transposed fmap ----------------
__global__ void zero16(uint4* __restrict__ p, int n) {
  int i = blockIdx.x * 256 + threadIdx.x;
  int stride = gridDim.x * 256;
  uint4 z; z.x = 0; z.y = 0; z.z = 0; z.w = 0;
  for (; i < n; i += stride) p[i] = z;
}

// ------- kernel 3b: fmap [b][i][y][x] f32 -> xt [b][y+1][x+1][i] bf16 (interior) -------
__global__ void transpose_pad(const float* __restrict__ fmap,
                              unsigned short* __restrict__ xt) {
  const int y = blockIdx.x;
  const int b = blockIdx.y;
  const int t = threadIdx.x;
  const int x = t & 63;
  const int ic0 = (t >> 6) * 8 + blockIdx.z * 256;
  const float* fb = fmap + (size_t)b * DIM * (HH * WW) + (size_t)y * WW + x;
  unsigned short* ob = xt + (((size_t)(b * HP + y + 1)) * WP + x + 1) * DIM;
  for (int r = 0; r < 8; ++r) {
    int i0 = ic0 + r * 32;
    s16x8 vv;
#pragma unroll
    for (int j = 0; j < 8; ++j)
      vv[j] = (short)f2bf(fb[(size_t)(i0 + j) * (HH * WW)]);
    *(s16x8*)&ob[i0] = vv;
  }
}

// ---------------- kernel 4: implicit-GEMM conv (m97 structure) ----------------
// Per batch: C[512 o][4096 p] = A[512][4608] * B^T, B'[p][k] = xt patch.
// Tile 128x128, BK=32, 4 waves each 64x64 (4x4 frags of 16x16x32 bf16 MFMA).
__global__ __launch_bounds__(256) void conv_gemm(
    const unsigned short* __restrict__ wts,  // [8][512][4608] bf16
    const unsigned short* __restrict__ xt,   // [8][66][72][512] bf16
    float* __restrict__ out) {               // [8][512][64][64] f32
  __shared__ unsigned short As[128 * 32];
  __shared__ unsigned short Bs[128 * 32];

  const int tid = threadIdx.x;
  const int wave = tid >> 6, lane = tid & 63;
  const int b = blockIdx.z;
  const int orow0 = blockIdx.y * 128;
  const int prow0 = blockIdx.x * 128;
  const int y0 = blockIdx.x * 2;          // two image rows per pixel tile

  const int wr = wave >> 1, wc = wave & 1;
  const int lr = lane & 15, lk = lane >> 4;
  const int srow = lane >> 2;             // staging: row within 16-row issue
  const int schunk = (lane & 3) * 8;      // staging: element chunk within row

  f32x4 acc[4][4] = {};

  const unsigned short* a_base = wts + (size_t)(b * 512 + orow0) * KTOT;
  const unsigned short* x_base = xt + (size_t)b * (HP * WP * DIM);

  for (int kykx = 0; kykx < 9; ++kykx) {
    const int ky = kykx / 3, kx = kykx - 3 * (kykx / 3);
    for (int is = 0; is < 16; ++is) {
      const int k0 = kykx * 512 + is * 32;
      const int i0 = is * 32;
      __syncthreads();  // previous compute done before LDS overwrite
#pragma unroll
      for (int j = 0; j < 2; ++j) {  // stage A: 2 x 1KB per wave
        int r = wave * 32 + j * 16 + srow;
        const unsigned short* gp = a_base + (size_t)r * KTOT + k0 + schunk;
        __builtin_amdgcn_global_load_lds(
            (const __attribute__((address_space(1))) void*)gp,
            (__attribute__((address_space(3))) void*)&As[(wave * 32 + j * 16) * 32],
            16, 0, 0);
      }
#pragma unroll
      for (int j = 0; j < 2; ++j) {  // stage B: 2 x 1KB per wave
        int r = wave * 32 + j * 16 + srow;
        int py = y0 + (r >> 6) + ky;
        int px = (r & 63) + kx;
        const unsigned short* gp = x_base + (((size_t)py * WP + px) << 9) + i0 + schunk;
        __builtin_amdgcn_global_load_lds(
            (const __attribute__((address_space(1))) void*)gp,
            (__attribute__((address_space(3))) void*)&Bs[(wave * 32 + j * 16) * 32],
            16, 0, 0);
      }
      __syncthreads();  // staged data visible

      s16x8 af[4], bfr[4];
#pragma unroll
      for (int mi = 0; mi < 4; ++mi)
        af[mi] = *(const s16x8*)&As[(wr * 64 + mi * 16 + lr) * 32 + lk * 8];
#pragma unroll
      for (int ni = 0; ni < 4; ++ni)
        bfr[ni] = *(const s16x8*)&Bs[(wc * 64 + ni * 16 + lr) * 32 + lk * 8];
#pragma unroll
      for (int mi = 0; mi < 4; ++mi)
#pragma unroll
        for (int ni = 0; ni < 4; ++ni)
          acc[mi][ni] = __builtin_amdgcn_mfma_f32_16x16x32_bf16(
              __builtin_bit_cast(bf16x8, af[mi]),
              __builtin_bit_cast(bf16x8, bfr[ni]), acc[mi][ni], 0, 0, 0);
    }
  }

  // epilogue: D layout col = lane&15 (pixel), row = (lane>>4)*4 + q (out-ch)
  float* obase = out + ((size_t)(b * 512 + orow0 + wr * 64) * 4096) + prow0 + wc * 64;
#pragma unroll
  for (int mi = 0; mi < 4; ++mi)
#pragma unroll
    for (int ni = 0; ni < 4; ++ni)
#pragma unroll
      for (int q = 0; q < 4; ++q)
        obase[(size_t)(mi * 16 + lk * 4 + q) * 4096 + ni * 16 + lr] = acc[mi][ni][q];
}

extern "C" void kernel_launch(void* const* d_in, const int* in_sizes, int n_in,
                              void* d_out, int out_size, void* d_ws, size_t ws_size,
                              hipStream_t stream) {
  const float* fmap    = (const float*)d_in[0];
  const float* embed   = (const float*)d_in[1];
  const float* wbank   = (const float*)d_in[2];
  const float* mod_w   = (const float*)d_in[3];
  const float* mod_b   = (const float*)d_in[4];
  const float* adapt_w = (const float*)d_in[5];
  const float* adapt_b = (const float*)d_in[6];
  float* out = (float*)d_out;

  char* ws = (char*)d_ws;
  float* sel = (float*)ws;                                   // 128 B
  float* mod = (float*)(ws + 256);                           // 16 KB
  unsigned short* wts = (unsigned short*)(ws + 256 + 16384); // 37,748,736 B
  unsigned short* xt  = (unsigned short*)(ws + 256 + 16384 + (size_t)NB * DIMO * KTOT * 2);
  // xt: 8*66*72*512*2 = 38,928,384 B ; total ws use ~76.7 MB

  int n16 = (int)((size_t)NB * HP * WP * DIM * 2 / 16);
  zero16<<<1024, 256, 0, stream>>>((uint4*)xt, n16);
  transpose_pad<<<dim3(64, 8, 2), 256, 0, stream>>>(fmap, xt);
  prep_selmod<<<8, 256, 0, stream>>>(embed, adapt_w, adapt_b, mod_w, mod_b, sel, mod);
  prep_weights<<<4096, 256, 0, stream>>>(wbank, sel, mod, wts);
  conv_gemm<<<dim3(32, 4, 8), 256, 0, stream>>>(wts, xt, out);
}

// Round 2
// 236.930 us; speedup vs baseline: 1.3153x; 1.3153x over previous
//
#include <hip/hip_runtime.h>
#include <stdint.h>

typedef short s16x8 __attribute__((ext_vector_type(8)));
typedef __bf16 bf16x8 __attribute__((ext_vector_type(8)));
typedef float f32x4 __attribute__((ext_vector_type(4)));

#define NB 8
#define DIM 512
#define DIMO 512
#define DEMB 512
#define NKER 4
#define HH 64
#define WW 64
#define HP 66
#define WP 72
#define KTOT 4608   // 9 * 512
#define NIT 36      // 72 K-steps of 64, 2 per iteration

__device__ __forceinline__ unsigned short f2bf(float f) {
  unsigned int u = __builtin_bit_cast(unsigned int, f);
  u += 0x7fffu + ((u >> 16) & 1u);
  return (unsigned short)(u >> 16);
}

// ---------------- kernel 1: sel (softmax over 4) + mod vectors ----------------
__global__ void prep_selmod(const float* __restrict__ embed,
                            const float* __restrict__ adapt_w,
                            const float* __restrict__ adapt_b,
                            const float* __restrict__ mod_w,
                            const float* __restrict__ mod_b,
                            float* __restrict__ sel, float* __restrict__ mod) {
  const int b = blockIdx.x;
  const int t = threadIdx.x;
  const float* e = embed + (size_t)b * DEMB;

  for (int rep = 0; rep < 2; ++rep) {
    int i = t + rep * 256;
    const float* wrow = mod_w + (size_t)i * DEMB;
    float s = 0.f;
    for (int j = 0; j < DEMB; ++j) s += e[j] * wrow[j];
    mod[b * DIM + i] = s + mod_b[i];
  }

  __shared__ float logits[NKER];
  if (t < NKER) {
    const float* arow = adapt_w + (size_t)t * DEMB;
    float s = 0.f;
    for (int j = 0; j < DEMB; ++j) s += e[j] * arow[j];
    logits[t] = s + adapt_b[t];
  }
  __syncthreads();
  if (t == 0) {
    float m = logits[0];
    for (int n = 1; n < NKER; ++n) m = fmaxf(m, logits[n]);
    float ex[NKER], sum = 0.f;
    for (int n = 0; n < NKER; ++n) { ex[n] = expf(logits[n] - m); sum += ex[n]; }
    for (int n = 0; n < NKER; ++n) sel[b * NKER + n] = ex[n] / sum;
  }
}

// ------- kernel 2: mix + modulate + demodulate weights -> bf16 [b][o][(ky*3+kx)*512+i] -------
__global__ void prep_weights(const float* __restrict__ wbank,
                             const float* __restrict__ sel,
                             const float* __restrict__ mod,
                             unsigned short* __restrict__ wts) {
  const int bo = blockIdx.x;
  const int b = bo >> 9;
  const int o = bo & 511;
  const int t = threadIdx.x;
  const size_t nstride = (size_t)DIMO * DIM * 9;

  __shared__ float v[KTOT];
  __shared__ float red[4];
  __shared__ float invn;

  const float s0 = sel[b * NKER + 0], s1 = sel[b * NKER + 1];
  const float s2 = sel[b * NKER + 2], s3 = sel[b * NKER + 3];
  const float* wb = wbank + (size_t)o * (DIM * 9);
  const float* mo = mod + b * DIM;

  float ss = 0.f;
  for (int r = 0; r < 18; ++r) {
    int ii = t + r * 256;
    int i = ii / 9;
    int kykx = ii - i * 9;
    float w = s0 * wb[ii] + s1 * wb[nstride + ii] + s2 * wb[2 * nstride + ii]
            + s3 * wb[3 * nstride + ii];
    w *= (mo[i] + 1.0f);
    v[kykx * 512 + i] = w;
    ss += w * w;
  }
  const int lane = t & 63, wv = t >> 6;
  for (int off = 32; off > 0; off >>= 1) ss += __shfl_down(ss, off);
  if (lane == 0) red[wv] = ss;
  __syncthreads();
  if (t == 0) {
    float tot = red[0] + red[1] + red[2] + red[3];
    tot = fmaxf(tot, 1e-8f);
    invn = rsqrtf(tot);
  }
  __syncthreads();
  const float inv = invn;
  unsigned short* wo = wts + (size_t)bo * KTOT;
  for (int r = 0; r < 18; ++r) {
    int ok = t + r * 256;
    wo[ok] = f2bf(v[ok] * inv);
  }
}

// ---------------- kernel 3a: zero padded transposed fmap ----------------
__global__ void zero16(uint4* __restrict__ p, int n) {
  int i = blockIdx.x * 256 + threadIdx.x;
  int stride = gridDim.x * 256;
  uint4 z; z.x = 0; z.y = 0; z.z = 0; z.w = 0;
  for (; i < n; i += stride) p[i] = z;
}

// ------- kernel 3b: fmap [b][i][y][x] f32 -> xt [b][y+1][x+1][i] bf16 (interior) -------
__global__ void transpose_pad(const float* __restrict__ fmap,
                              unsigned short* __restrict__ xt) {
  const int y = blockIdx.x;
  const int b = blockIdx.y;
  const int t = threadIdx.x;
  const int x = t & 63;
  const int ic0 = (t >> 6) * 8 + blockIdx.z * 256;
  const float* fb = fmap + (size_t)b * DIM * (HH * WW) + (size_t)y * WW + x;
  unsigned short* ob = xt + (((size_t)(b * HP + y + 1)) * WP + x + 1) * DIM;
  for (int r = 0; r < 8; ++r) {
    int i0 = ic0 + r * 32;
    s16x8 vv;
#pragma unroll
    for (int j = 0; j < 8; ++j)
      vv[j] = (short)f2bf(fb[(size_t)(i0 + j) * (HH * WW)]);
    *(s16x8*)&ob[i0] = vv;
  }
}

// ---------------- kernel 4: implicit-GEMM conv, 256x256 tile, 8-phase schedule ----------------
// Per batch: C[512 o][4096 p] = A[512][4608] . B[4096][4608]^T (both K-contiguous).
// BM=BN=256, BK=64, 8 waves (2M x 4N), per-wave 128x64. LDS 128KB: 2 dbuf x (A 32KB + B 32KB).
// Per phase: stage 1 half-tile (2 x global_load_lds w=16), ds-read one block-quadrant's operand
// subtile (XOR-swizzled), counted vmcnt(4) (never 0 in main loop), 1 barrier, 16 MFMA w/ setprio.
// Quadrant gray order (0,0),(0,1),(1,1),(1,0) so each phase consumes exactly one fresh half-tile.
// Paper-verified schedule: every half-tile guaranteed by vmcnt >=2 phases after issue + barrier
// before first read; every LDS region restaged >=4 phases after last read.
__global__ __launch_bounds__(512, 2) void conv_gemm(
    const unsigned short* __restrict__ wts,  // [8][512][4608] bf16
    const unsigned short* __restrict__ xt,   // [8][66][72][512] bf16
    float* __restrict__ out) {               // [8][512][64][64] f32
  extern __shared__ __attribute__((aligned(16))) char smem[];

  const int tid = threadIdx.x;
  const int w = tid >> 6, l = tid & 63;
  const int bid = blockIdx.x;
  const int b = bid >> 5;
  const int mt = (bid >> 4) & 1;
  const int nt = bid & 15;
  const int orow0 = mt << 8;
  const int prow0 = nt << 8;
  const int y0 = nt << 2;                  // 4 image rows per 256-pixel tile
  const int wm = w >> 2, wn = w & 3;       // 2 x 4 wave grid
  const int lr = l & 15, lk = l >> 4;

  const unsigned short* a_base = wts + (size_t)(b * 512 + orow0) * KTOT;
  const unsigned short* x_base = xt + (size_t)b * (HP * WP * DIM);

  // staging geometry: issue j covers 64 rows (128B each); LDS dest linear, source pre-swizzled
  const int srow = (w << 3) + (l >> 3);                 // row within 64-row issue
  const int sx8 = (((l & 7) ^ ((l >> 3) & 7)) << 3);    // source chunk (elements), involution
  // fragment-read geometry: chunk slot = (s*4+lk) ^ (row&7), row&7 == l&7 for all frags
  const int sw0 = ((lk ^ (l & 7)) << 4);                // byte offset, s=0 (s=1: ^64)
  const int aRow = (((wm << 6) + lr) << 7);             // (wm*64+lr)*128 bytes
  const int bRow = (((wn << 5) + lr) << 7);

  f32x4 acc[2][2][4][2] = {};   // [mq][nq][mi][nj] - all indices compile-time (rule #20)
  s16x8 aF[2][4], bF0[2][2], bF1[2][2];

  auto stageA = [&](int d, int h, int ks) {
#pragma unroll
    for (int j = 0; j < 2; ++j) {
      const unsigned short* gp = a_base + (size_t)((h << 7) + (j << 6) + srow) * KTOT
                               + (ks << 6) + sx8;
      __builtin_amdgcn_global_load_lds(
          (const __attribute__((address_space(1))) void*)gp,
          (__attribute__((address_space(3))) void*)(smem + (d << 16) + (h << 14) + (j << 13) + (w << 10)),
          16, 0, 0);
    }
  };
  auto stageB = [&](int d, int h, int ks) {
    const int kykx = ks >> 3;
    const int ky = kykx / 3, kx = kykx - 3 * (kykx / 3);
    const int i0 = (ks & 7) << 6;
#pragma unroll
    for (int j = 0; j < 2; ++j) {
      const int pl = (h << 7) + (j << 6) + srow;
      const int py = y0 + (pl >> 6) + ky;
      const int px = (pl & 63) + kx;
      const unsigned short* gp = x_base + (((size_t)py * WP + px) << 9) + i0 + sx8;
      __builtin_amdgcn_global_load_lds(
          (const __attribute__((address_space(1))) void*)gp,
          (__attribute__((address_space(3))) void*)(smem + (d << 16) + 32768 + (h << 14) + (j << 13) + (w << 10)),
          16, 0, 0);
    }
  };

#define VM4 asm volatile("s_waitcnt vmcnt(4)" ::: "memory")
#define VM2 asm volatile("s_waitcnt vmcnt(2)" ::: "memory")
#define VM0 asm volatile("s_waitcnt vmcnt(0)" ::: "memory")
#define FENCE asm volatile("" ::: "memory")
#define BAR do { FENCE; __builtin_amdgcn_s_barrier(); FENCE; } while (0)

#define LOAD_A(d, mq) \
  _Pragma("unroll") for (int s = 0; s < 2; ++s) \
  _Pragma("unroll") for (int mi = 0; mi < 4; ++mi) \
    aF[s][mi] = *(const s16x8*)(smem + ((d) << 16) + ((mq) << 14) + aRow + (mi << 11) + (sw0 ^ (s << 6)));

#define LOAD_B(d, nq, BF) \
  _Pragma("unroll") for (int s = 0; s < 2; ++s) \
  _Pragma("unroll") for (int nj = 0; nj < 2; ++nj) \
    BF[s][nj] = *(const s16x8*)(smem + ((d) << 16) + 32768 + ((nq) << 14) + bRow + (nj << 11) + (sw0 ^ (s << 6)));

#define MFMA_Q(mq, nq, BF) do { \
  __builtin_amdgcn_s_setprio(1); \
  _Pragma("unroll") for (int s = 0; s < 2; ++s) \
  _Pragma("unroll") for (int mi = 0; mi < 4; ++mi) \
  _Pragma("unroll") for (int nj = 0; nj < 2; ++nj) \
    acc[mq][nq][mi][nj] = __builtin_amdgcn_mfma_f32_16x16x32_bf16( \
        __builtin_bit_cast(bf16x8, aF[s][mi]), __builtin_bit_cast(bf16x8, BF[s][nj]), \
        acc[mq][nq][mi][nj], 0, 0, 0); \
  __builtin_amdgcn_s_setprio(0); \
} while (0)

  // prologue: stage buf0 <- ks=0 in consumption-aligned order A0,B0,B1,A1
  stageA(0, 0, 0); stageB(0, 0, 0); stageB(0, 1, 0); stageA(0, 1, 0);
  VM4; BAR;   // A0,B0 of ks=0 visible to all waves

  for (int it = 0; it < NIT - 1; ++it) {
    const int ks1 = 2 * it + 1, ks2 = 2 * it + 2;
    // phases 1-4: compute buf0 (ks=2it), stage buf1 <- ks1
    stageA(1, 0, ks1); LOAD_A(0, 0); LOAD_B(0, 0, bF0); VM4; BAR; MFMA_Q(0, 0, bF0);
    stageB(1, 0, ks1); LOAD_B(0, 1, bF1);               VM4; BAR; MFMA_Q(0, 1, bF1);
    stageB(1, 1, ks1); LOAD_A(0, 1);                         BAR; MFMA_Q(1, 1, bF1);
    stageA(1, 1, ks1);                                  VM4; BAR; MFMA_Q(1, 0, bF0);
    // phases 5-8: compute buf1 (ks1), stage buf0 <- ks2
    stageA(0, 0, ks2); LOAD_A(1, 0); LOAD_B(1, 0, bF0); VM4; BAR; MFMA_Q(0, 0, bF0);
    stageB(0, 0, ks2); LOAD_B(1, 1, bF1);               VM4; BAR; MFMA_Q(0, 1, bF1);
    stageB(0, 1, ks2); LOAD_A(1, 1);                         BAR; MFMA_Q(1, 1, bF1);
    stageA(0, 1, ks2);                                  VM4; BAR; MFMA_Q(1, 0, bF0);
  }
  { // last iteration: no ks2 staging; drain with counted waits 4->2->0
    const int ks1 = 2 * (NIT - 1) + 1;
    stageA(1, 0, ks1); LOAD_A(0, 0); LOAD_B(0, 0, bF0); VM4; BAR; MFMA_Q(0, 0, bF0);
    stageB(1, 0, ks1); LOAD_B(0, 1, bF1);               VM4; BAR; MFMA_Q(0, 1, bF1);
    stageB(1, 1, ks1); LOAD_A(0, 1);                         BAR; MFMA_Q(1, 1, bF1);
    stageA(1, 1, ks1);                                  VM4; BAR; MFMA_Q(1, 0, bF0);
    LOAD_A(1, 0); LOAD_B(1, 0, bF0);                    VM2; BAR; MFMA_Q(0, 0, bF0);
    LOAD_B(1, 1, bF1);                                  VM0; BAR; MFMA_Q(0, 1, bF1);
    LOAD_A(1, 1);                                            BAR; MFMA_Q(1, 1, bF1);
                                                             BAR; MFMA_Q(1, 0, bF0);
  }

  // epilogue: D layout col=lane&15 (pixel), row=(lane>>4)*4+q (out-channel)
#pragma unroll
  for (int mq = 0; mq < 2; ++mq)
#pragma unroll
  for (int nq = 0; nq < 2; ++nq)
#pragma unroll
  for (int mi = 0; mi < 4; ++mi)
#pragma unroll
  for (int nj = 0; nj < 2; ++nj) {
    float* ob = out
      + ((size_t)(b * 512 + orow0 + (mq << 7) + (wm << 6) + (mi << 4) + (lk << 2)) << 12)
      + prow0 + (nq << 7) + (wn << 5) + (nj << 4) + lr;
#pragma unroll
    for (int q = 0; q < 4; ++q)
      ob[(size_t)q << 12] = acc[mq][nq][mi][nj][q];
  }
#undef VM4
#undef VM2
#undef VM0
#undef FENCE
#undef BAR
#undef LOAD_A
#undef LOAD_B
#undef MFMA_Q
}

extern "C" void kernel_launch(void* const* d_in, const int* in_sizes, int n_in,
                              void* d_out, int out_size, void* d_ws, size_t ws_size,
                              hipStream_t stream) {
  const float* fmap    = (const float*)d_in[0];
  const float* embed   = (const float*)d_in[1];
  const float* wbank   = (const float*)d_in[2];
  const float* mod_w   = (const float*)d_in[3];
  const float* mod_b   = (const float*)d_in[4];
  const float* adapt_w = (const float*)d_in[5];
  const float* adapt_b = (const float*)d_in[6];
  float* out = (float*)d_out;

  char* ws = (char*)d_ws;
  float* sel = (float*)ws;                                   // 128 B
  float* mod = (float*)(ws + 256);                           // 16 KB
  unsigned short* wts = (unsigned short*)(ws + 256 + 16384); // 37,748,736 B
  unsigned short* xt  = (unsigned short*)(ws + 256 + 16384 + (size_t)NB * DIMO * KTOT * 2);
  // xt: 8*66*72*512*2 = 38,928,384 B ; total ws use ~76.7 MB

  int n16 = (int)((size_t)NB * HP * WP * DIM * 2 / 16);
  zero16<<<1024, 256, 0, stream>>>((uint4*)xt, n16);
  transpose_pad<<<dim3(64, 8, 2), 256, 0, stream>>>(fmap, xt);
  prep_selmod<<<8, 256, 0, stream>>>(embed, adapt_w, adapt_b, mod_w, mod_b, sel, mod);
  prep_weights<<<4096, 256, 0, stream>>>(wbank, sel, mod, wts);

  // 128 KiB dynamic LDS needs the opt-in attribute (idempotent, capture-safe host call)
  (void)hipFuncSetAttribute((const void*)conv_gemm,
                            hipFuncAttributeMaxDynamicSharedMemorySize, 131072);
  conv_gemm<<<dim3(256), dim3(512), 131072, stream>>>(wts, xt, out);
}

// Round 3
// 209.791 us; speedup vs baseline: 1.4854x; 1.1294x over previous
//
#include <hip/hip_runtime.h>
#include <stdint.h>

typedef short s16x8 __attribute__((ext_vector_type(8)));
typedef __bf16 bf16x8 __attribute__((ext_vector_type(8)));
typedef float f32x4 __attribute__((ext_vector_type(4)));

#define NB 8
#define DIM 512
#define DIMO 512
#define DEMB 512
#define NKER 4
#define HH 64
#define WW 64
#define HP 66
#define WP 72
#define KTOT 4608   // 9 * 512
#define NIT 36      // 72 K-steps of 64, 2 per iteration

__device__ __forceinline__ unsigned short f2bf(float f) {
  unsigned int u = __builtin_bit_cast(unsigned int, f);
  u += 0x7fffu + ((u >> 16) & 1u);
  return (unsigned short)(u >> 16);
}

// ---------------- kernel 1: sel (softmax over 4) + mod vectors ----------------
__global__ void prep_selmod(const float* __restrict__ embed,
                            const float* __restrict__ adapt_w,
                            const float* __restrict__ adapt_b,
                            const float* __restrict__ mod_w,
                            const float* __restrict__ mod_b,
                            float* __restrict__ sel, float* __restrict__ mod) {
  const int b = blockIdx.x;
  const int t = threadIdx.x;
  const float* e = embed + (size_t)b * DEMB;

  for (int rep = 0; rep < 2; ++rep) {
    int i = t + rep * 256;
    const float* wrow = mod_w + (size_t)i * DEMB;
    float s = 0.f;
    for (int j = 0; j < DEMB; ++j) s += e[j] * wrow[j];
    mod[b * DIM + i] = s + mod_b[i];
  }

  __shared__ float logits[NKER];
  if (t < NKER) {
    const float* arow = adapt_w + (size_t)t * DEMB;
    float s = 0.f;
    for (int j = 0; j < DEMB; ++j) s += e[j] * arow[j];
    logits[t] = s + adapt_b[t];
  }
  __syncthreads();
  if (t == 0) {
    float m = logits[0];
    for (int n = 1; n < NKER; ++n) m = fmaxf(m, logits[n]);
    float ex[NKER], sum = 0.f;
    for (int n = 0; n < NKER; ++n) { ex[n] = expf(logits[n] - m); sum += ex[n]; }
    for (int n = 0; n < NKER; ++n) sel[b * NKER + n] = ex[n] / sum;
  }
}

// ------- kernel 2: per-o block; stage bank rows in LDS once, loop over b -------
// out layout: wts[b][o][(ky*3+kx)*512+i] bf16
__global__ void prep_weights(const float* __restrict__ wbank,
                             const float* __restrict__ sel,
                             const float* __restrict__ mod,
                             unsigned short* __restrict__ wts) {
  const int o = blockIdx.x;          // 512 blocks
  const int t = threadIdx.x;         // 256 threads
  extern __shared__ float ls[];      // [4][4608] linear (i*9+kykx) order
  __shared__ float red[4];

  // stage: coalesced global reads, linear LDS writes (conflict-free)
#pragma unroll
  for (int n = 0; n < NKER; ++n) {
    const float* wb = wbank + ((size_t)n * DIMO + o) * (DIM * 9);
#pragma unroll
    for (int r = 0; r < 18; ++r) {
      int ii = t + r * 256;
      ls[n * KTOT + ii] = wb[ii];
    }
  }
  __syncthreads();

  const int lane = t & 63, wv = t >> 6;
  for (int b = 0; b < NB; ++b) {
    const float s0 = sel[b * NKER + 0], s1 = sel[b * NKER + 1];
    const float s2 = sel[b * NKER + 2], s3 = sel[b * NKER + 3];
    const float* mo = mod + b * DIM;

    float v[18];
    float ss = 0.f;
#pragma unroll
    for (int r = 0; r < 18; ++r) {
      int ok = t + r * 256;                 // output slot: kykx*512 + i
      int src = (ok & 511) * 9 + (ok >> 9); // stride-9 LDS read: 2-way conflict (free)
      float w = s0 * ls[src] + s1 * ls[KTOT + src]
              + s2 * ls[2 * KTOT + src] + s3 * ls[3 * KTOT + src];
      w *= (mo[ok & 511] + 1.0f);
      v[r] = w;
      ss += w * w;
    }
    for (int off = 32; off > 0; off >>= 1) ss += __shfl_down(ss, off);
    if (lane == 0) red[wv] = ss;
    __syncthreads();
    float tot = red[0] + red[1] + red[2] + red[3];
    float inv = rsqrtf(fmaxf(tot, 1e-8f));
    unsigned short* wo = wts + ((size_t)(b * DIMO + o)) * KTOT;
#pragma unroll
    for (int r = 0; r < 18; ++r)
      wo[t + r * 256] = f2bf(v[r] * inv);
    __syncthreads();   // protect red[] before next b
  }
}

// ---------------- kernel 3a: zero only the halo of xt ----------------
// halo pixels per b: row y=0 (72), row y=65 (72), rows 1..64 x in {0,65..71} (8 each)
__global__ void halo_zero(unsigned short* __restrict__ xt) {
  const int b = blockIdx.y;
  const int h = blockIdx.x;  // 0..655
  int py, px;
  if (h < 72) { py = 0; px = h; }
  else if (h < 144) { py = 65; px = h - 72; }
  else { int e = h - 144; py = 1 + (e >> 3); int c = e & 7; px = c ? 64 + c : 0; }
  uint4* p = (uint4*)(xt + (((size_t)(b * HP + py)) * WP + px) * DIM);
  uint4 z; z.x = 0; z.y = 0; z.z = 0; z.w = 0;
  p[threadIdx.x] = z;   // 64 threads x 16B = 1KB = 512 ch
}

// ------- kernel 3b: fmap [b][i][y][x] f32 -> xt [b][y+1][x+1][i] bf16 (interior) -------
__global__ void transpose_pad(const float* __restrict__ fmap,
                              unsigned short* __restrict__ xt) {
  const int y = blockIdx.x;
  const int b = blockIdx.y;
  const int t = threadIdx.x;
  const int x = t & 63;
  const int ic0 = (t >> 6) * 8 + blockIdx.z * 256;
  const float* fb = fmap + (size_t)b * DIM * (HH * WW) + (size_t)y * WW + x;
  unsigned short* ob = xt + (((size_t)(b * HP + y + 1)) * WP + x + 1) * DIM;
  for (int r = 0; r < 8; ++r) {
    int i0 = ic0 + r * 32;
    s16x8 vv;
#pragma unroll
    for (int j = 0; j < 8; ++j)
      vv[j] = (short)f2bf(fb[(size_t)(i0 + j) * (HH * WW)]);
    *(s16x8*)&ob[i0] = vv;
  }
}

// ---------------- kernel 4: implicit-GEMM conv, 256x256 tile, 8-phase schedule ----------------
// Per batch: C[512 o][4096 p] = A[512][4608] . B[4096][4608]^T (both K-contiguous).
// BM=BN=256, BK=64, 8 waves (2M x 4N), per-wave 128x64. LDS 128KB: 2 dbuf x (A 32KB + B 32KB).
// XCD-chunked block swizzle: XCD i owns batch i (A-panel 16x reuse within one L2).
__global__ __launch_bounds__(512, 2) void conv_gemm(
    const unsigned short* __restrict__ wts,  // [8][512][4608] bf16
    const unsigned short* __restrict__ xt,   // [8][66][72][512] bf16
    float* __restrict__ out) {               // [8][512][64][64] f32
  extern __shared__ __attribute__((aligned(16))) char smem[];

  const int tid = threadIdx.x;
  const int w = tid >> 6, l = tid & 63;
  const int bid0 = blockIdx.x;
  const int bid = ((bid0 & 7) << 5) | (bid0 >> 3);   // T1: 8 XCDs x 32 blocks, bijective
  const int b = bid >> 5;
  const int mt = (bid >> 4) & 1;
  const int nt = bid & 15;
  const int orow0 = mt << 8;
  const int prow0 = nt << 8;
  const int y0 = nt << 2;                  // 4 image rows per 256-pixel tile
  const int wm = w >> 2, wn = w & 3;       // 2 x 4 wave grid
  const int lr = l & 15, lk = l >> 4;

  const unsigned short* a_base = wts + (size_t)(b * 512 + orow0) * KTOT;
  const unsigned short* x_base = xt + (size_t)b * (HP * WP * DIM);

  const int srow = (w << 3) + (l >> 3);                 // row within 64-row issue
  const int sx8 = (((l & 7) ^ ((l >> 3) & 7)) << 3);    // source chunk (elements), involution
  const int sw0 = ((lk ^ (l & 7)) << 4);                // frag-read byte offset, s=0 (s=1: ^64)
  const int aRow = (((wm << 6) + lr) << 7);
  const int bRow = (((wn << 5) + lr) << 7);

  f32x4 acc[2][2][4][2] = {};
  s16x8 aF[2][4], bF0[2][2], bF1[2][2];

  auto stageA = [&](int d, int h, int ks) {
#pragma unroll
    for (int j = 0; j < 2; ++j) {
      const unsigned short* gp = a_base + (size_t)((h << 7) + (j << 6) + srow) * KTOT
                               + (ks << 6) + sx8;
      __builtin_amdgcn_global_load_lds(
          (const __attribute__((address_space(1))) void*)gp,
          (__attribute__((address_space(3))) void*)(smem + (d << 16) + (h << 14) + (j << 13) + (w << 10)),
          16, 0, 0);
    }
  };
  auto stageB = [&](int d, int h, int ks) {
    const int kykx = ks >> 3;
    const int ky = kykx / 3, kx = kykx - 3 * (kykx / 3);
    const int i0 = (ks & 7) << 6;
#pragma unroll
    for (int j = 0; j < 2; ++j) {
      const int pl = (h << 7) + (j << 6) + srow;
      const int py = y0 + (pl >> 6) + ky;
      const int px = (pl & 63) + kx;
      const unsigned short* gp = x_base + (((size_t)py * WP + px) << 9) + i0 + sx8;
      __builtin_amdgcn_global_load_lds(
          (const __attribute__((address_space(1))) void*)gp,
          (__attribute__((address_space(3))) void*)(smem + (d << 16) + 32768 + (h << 14) + (j << 13) + (w << 10)),
          16, 0, 0);
    }
  };

#define VM4 asm volatile("s_waitcnt vmcnt(4)" ::: "memory")
#define VM2 asm volatile("s_waitcnt vmcnt(2)" ::: "memory")
#define VM0 asm volatile("s_waitcnt vmcnt(0)" ::: "memory")
#define FENCE asm volatile("" ::: "memory")
#define BAR do { FENCE; __builtin_amdgcn_s_barrier(); FENCE; } while (0)

#define LOAD_A(d, mq) \
  _Pragma("unroll") for (int s = 0; s < 2; ++s) \
  _Pragma("unroll") for (int mi = 0; mi < 4; ++mi) \
    aF[s][mi] = *(const s16x8*)(smem + ((d) << 16) + ((mq) << 14) + aRow + (mi << 11) + (sw0 ^ (s << 6)));

#define LOAD_B(d, nq, BF) \
  _Pragma("unroll") for (int s = 0; s < 2; ++s) \
  _Pragma("unroll") for (int nj = 0; nj < 2; ++nj) \
    BF[s][nj] = *(const s16x8*)(smem + ((d) << 16) + 32768 + ((nq) << 14) + bRow + (nj << 11) + (sw0 ^ (s << 6)));

#define MFMA_Q(mq, nq, BF) do { \
  __builtin_amdgcn_s_setprio(1); \
  _Pragma("unroll") for (int s = 0; s < 2; ++s) \
  _Pragma("unroll") for (int mi = 0; mi < 4; ++mi) \
  _Pragma("unroll") for (int nj = 0; nj < 2; ++nj) \
    acc[mq][nq][mi][nj] = __builtin_amdgcn_mfma_f32_16x16x32_bf16( \
        __builtin_bit_cast(bf16x8, aF[s][mi]), __builtin_bit_cast(bf16x8, BF[s][nj]), \
        acc[mq][nq][mi][nj], 0, 0, 0); \
  __builtin_amdgcn_s_setprio(0); \
} while (0)

  // prologue: stage buf0 <- ks=0 in consumption-aligned order A0,B0,B1,A1
  stageA(0, 0, 0); stageB(0, 0, 0); stageB(0, 1, 0); stageA(0, 1, 0);
  VM4; BAR;

  for (int it = 0; it < NIT - 1; ++it) {
    const int ks1 = 2 * it + 1, ks2 = 2 * it + 2;
    stageA(1, 0, ks1); LOAD_A(0, 0); LOAD_B(0, 0, bF0); VM4; BAR; MFMA_Q(0, 0, bF0);
    stageB(1, 0, ks1); LOAD_B(0, 1, bF1);               VM4; BAR; MFMA_Q(0, 1, bF1);
    stageB(1, 1, ks1); LOAD_A(0, 1);                         BAR; MFMA_Q(1, 1, bF1);
    stageA(1, 1, ks1);                                  VM4; BAR; MFMA_Q(1, 0, bF0);
    stageA(0, 0, ks2); LOAD_A(1, 0); LOAD_B(1, 0, bF0); VM4; BAR; MFMA_Q(0, 0, bF0);
    stageB(0, 0, ks2); LOAD_B(1, 1, bF1);               VM4; BAR; MFMA_Q(0, 1, bF1);
    stageB(0, 1, ks2); LOAD_A(1, 1);                         BAR; MFMA_Q(1, 1, bF1);
    stageA(0, 1, ks2);                                  VM4; BAR; MFMA_Q(1, 0, bF0);
  }
  {
    const int ks1 = 2 * (NIT - 1) + 1;
    stageA(1, 0, ks1); LOAD_A(0, 0); LOAD_B(0, 0, bF0); VM4; BAR; MFMA_Q(0, 0, bF0);
    stageB(1, 0, ks1); LOAD_B(0, 1, bF1);               VM4; BAR; MFMA_Q(0, 1, bF1);
    stageB(1, 1, ks1); LOAD_A(0, 1);                         BAR; MFMA_Q(1, 1, bF1);
    stageA(1, 1, ks1);                                  VM4; BAR; MFMA_Q(1, 0, bF0);
    LOAD_A(1, 0); LOAD_B(1, 0, bF0);                    VM2; BAR; MFMA_Q(0, 0, bF0);
    LOAD_B(1, 1, bF1);                                  VM0; BAR; MFMA_Q(0, 1, bF1);
    LOAD_A(1, 1);                                            BAR; MFMA_Q(1, 1, bF1);
                                                             BAR; MFMA_Q(1, 0, bF0);
  }

  // epilogue: D layout col=lane&15 (pixel), row=(lane>>4)*4+q (out-channel)
#pragma unroll
  for (int mq = 0; mq < 2; ++mq)
#pragma unroll
  for (int nq = 0; nq < 2; ++nq)
#pragma unroll
  for (int mi = 0; mi < 4; ++mi)
#pragma unroll
  for (int nj = 0; nj < 2; ++nj) {
    float* ob = out
      + ((size_t)(b * 512 + orow0 + (mq << 7) + (wm << 6) + (mi << 4) + (lk << 2)) << 12)
      + prow0 + (nq << 7) + (wn << 5) + (nj << 4) + lr;
#pragma unroll
    for (int q = 0; q < 4; ++q)
      ob[(size_t)q << 12] = acc[mq][nq][mi][nj][q];
  }
#undef VM4
#undef VM2
#undef VM0
#undef FENCE
#undef BAR
#undef LOAD_A
#undef LOAD_B
#undef MFMA_Q
}

extern "C" void kernel_launch(void* const* d_in, const int* in_sizes, int n_in,
                              void* d_out, int out_size, void* d_ws, size_t ws_size,
                              hipStream_t stream) {
  const float* fmap    = (const float*)d_in[0];
  const float* embed   = (const float*)d_in[1];
  const float* wbank   = (const float*)d_in[2];
  const float* mod_w   = (const float*)d_in[3];
  const float* mod_b   = (const float*)d_in[4];
  const float* adapt_w = (const float*)d_in[5];
  const float* adapt_b = (const float*)d_in[6];
  float* out = (float*)d_out;

  char* ws = (char*)d_ws;
  float* sel = (float*)ws;                                   // 128 B
  float* mod = (float*)(ws + 256);                           // 16 KB
  unsigned short* wts = (unsigned short*)(ws + 256 + 16384); // 37,748,736 B
  unsigned short* xt  = (unsigned short*)(ws + 256 + 16384 + (size_t)NB * DIMO * KTOT * 2);
  // xt: 8*66*72*512*2 = 38,928,384 B ; total ws use ~76.7 MB

  halo_zero<<<dim3(656, 8), 64, 0, stream>>>(xt);
  transpose_pad<<<dim3(64, 8, 2), 256, 0, stream>>>(fmap, xt);
  prep_selmod<<<8, 256, 0, stream>>>(embed, adapt_w, adapt_b, mod_w, mod_b, sel, mod);

  (void)hipFuncSetAttribute((const void*)prep_weights,
                            hipFuncAttributeMaxDynamicSharedMemorySize, 73728);
  prep_weights<<<512, 256, 73728, stream>>>(wbank, sel, mod, wts);

  (void)hipFuncSetAttribute((const void*)conv_gemm,
                            hipFuncAttributeMaxDynamicSharedMemorySize, 131072);
  conv_gemm<<<dim3(256), dim3(512), 131072, stream>>>(wts, xt, out);
}